// Round 4
// baseline (965.650 us; speedup 1.0000x reference)
//
#include <hip/hip_runtime.h>
#include <math.h>

#define B_SZ 2
#define T_SEQ 2048
#define DM 1024
#define NH 16
#define DH 64
#define ROWS (B_SZ * T_SEQ)  // 4096
#define LN_EPS 1e-5f

typedef __attribute__((ext_vector_type(8))) short short8;
typedef __attribute__((ext_vector_type(4))) float floatx4;

__device__ __forceinline__ short f2bf(float f) {
    union { float f; unsigned u; } v; v.f = f;
    unsigned r = v.u + 0x7fffu + ((v.u >> 16) & 1u);  // RNE
    return (short)(r >> 16);
}
__device__ __forceinline__ float bf2f(short s) {
    union { float f; unsigned u; } v; v.u = ((unsigned)(unsigned short)s) << 16;
    return v.f;
}
__device__ __forceinline__ short8 ld8(const short* p) {  // 8B-aligned pair of b64
    short4 a = *(const short4*)p;
    short4 b = *(const short4*)(p + 4);
    return short8{a.x, a.y, a.z, a.w, b.x, b.y, b.z, b.w};
}
// async 16B global->LDS (lds dest = wave-uniform base + lane*16)
__device__ __forceinline__ void gl2lds16(const void* g, void* l) {
    __builtin_amdgcn_global_load_lds(
        (const __attribute__((address_space(1))) unsigned int*)g,
        (__attribute__((address_space(3))) unsigned int*)l, 16, 0, 0);
}

// ---------------------------------------------------------------- LayerNorm (bf16 out)
__global__ __launch_bounds__(256) void ln_kernel(const float* __restrict__ x,
                                                 const float* __restrict__ g,
                                                 const float* __restrict__ bta,
                                                 short* __restrict__ h) {
    int row = blockIdx.x;
    const float* xr = x + (size_t)row * DM;
    int tid = threadIdx.x;
    float4 v = ((const float4*)xr)[tid];
    float s = v.x + v.y + v.z + v.w;
    float ss = v.x * v.x + v.y * v.y + v.z * v.z + v.w * v.w;
    for (int off = 1; off < 64; off <<= 1) {
        s += __shfl_xor(s, off);
        ss += __shfl_xor(ss, off);
    }
    __shared__ float sbuf[4], ssbuf[4];
    int wave = tid >> 6, lane = tid & 63;
    if (lane == 0) { sbuf[wave] = s; ssbuf[wave] = ss; }
    __syncthreads();
    s = sbuf[0] + sbuf[1] + sbuf[2] + sbuf[3];
    ss = ssbuf[0] + ssbuf[1] + ssbuf[2] + ssbuf[3];
    float mu = s * (1.0f / DM);
    float var = ss * (1.0f / DM) - mu * mu;
    float rs = rsqrtf(var + LN_EPS);
    float4 gg = ((const float4*)g)[tid];
    float4 bb = ((const float4*)bta)[tid];
    short4 o;
    o.x = f2bf((v.x - mu) * rs * gg.x + bb.x);
    o.y = f2bf((v.y - mu) * rs * gg.y + bb.y);
    o.z = f2bf((v.z - mu) * rs * gg.z + bb.z);
    o.w = f2bf((v.w - mu) * rs * gg.w + bb.w);
    *(short4*)&h[(size_t)row * DM + tid * 4] = o;
}

// ------------------------------------------- weight convert+transpose fp32[K,N]->bf16[N,K]
__global__ __launch_bounds__(256) void wt_kernel(const float* __restrict__ W,
                                                 short* __restrict__ Wt, int K, int N) {
    __shared__ float t[32][33];
    int tx = threadIdx.x & 31, ty = threadIdx.x >> 5;  // ty 0..7
    int k0 = blockIdx.y * 32, n0 = blockIdx.x * 32;
    for (int p = 0; p < 4; ++p)
        t[ty + 8 * p][tx] = W[(size_t)(k0 + ty + 8 * p) * N + n0 + tx];
    __syncthreads();
    for (int p = 0; p < 4; ++p)
        Wt[(size_t)(n0 + ty + 8 * p) * K + k0 + tx] = f2bf(t[tx][ty + 8 * p]);
}

// ------------------------------------------------------- bf16 MFMA GEMM (m97 structure)
// C[M,N] = A[M,K]bf16 @ Bt[N,K]bf16^T + bias; 128x128 tile, BK=32, 4 waves x 64x64.
template <bool RESID, bool BF16_OUT>
__global__ __launch_bounds__(256) void mfma_gemm(const short* __restrict__ A,
                                                 const short* __restrict__ Bt,
                                                 const float* __restrict__ bias,
                                                 const float* __restrict__ resid,
                                                 void* __restrict__ Cout,
                                                 int M, int N, int K) {
    __shared__ short As[128 * 32];
    __shared__ short Bs[128 * 32];
    int tid = threadIdx.x;
    int wave = tid >> 6, lane = tid & 63;
    int l15 = lane & 15, quad = lane >> 4;
    int wm = wave & 1, wn = wave >> 1;
    int row0 = blockIdx.y * 128, col0 = blockIdx.x * 128;

    floatx4 acc[4][4] = {};
    for (int k0 = 0; k0 < K; k0 += 32) {
        __syncthreads();
        for (int i = 0; i < 2; ++i) {
            int c = (wave * 2 + i) * 64 + lane;  // 16B chunk id, 512 per tile
            int row = c >> 2, kc = c & 3;
            gl2lds16(A + (size_t)(row0 + row) * K + k0 + kc * 8, &As[(wave * 2 + i) * 512]);
            gl2lds16(Bt + (size_t)(col0 + row) * K + k0 + kc * 8, &Bs[(wave * 2 + i) * 512]);
        }
        __syncthreads();  // drains vmcnt (global_load_lds) per barrier semantics
        short8 af[4], bfr[4];
        for (int m = 0; m < 4; ++m)
            af[m] = *(const short8*)&As[(wm * 64 + m * 16 + l15) * 32 + quad * 8];
        for (int n = 0; n < 4; ++n)
            bfr[n] = *(const short8*)&Bs[(wn * 64 + n * 16 + l15) * 32 + quad * 8];
        for (int m = 0; m < 4; ++m)
            for (int n = 0; n < 4; ++n)
                acc[m][n] = __builtin_amdgcn_mfma_f32_16x16x32_bf16(af[m], bfr[n], acc[m][n], 0, 0, 0);
    }
    float bias_v[4];
    for (int n = 0; n < 4; ++n) bias_v[n] = bias[col0 + wn * 64 + n * 16 + l15];
    for (int m = 0; m < 4; ++m)
        for (int r = 0; r < 4; ++r) {
            int rg = row0 + wm * 64 + m * 16 + quad * 4 + r;
            for (int n = 0; n < 4; ++n) {
                int cg = col0 + wn * 64 + n * 16 + l15;
                float v = acc[m][n][r] + bias_v[n];
                if (BF16_OUT) {
                    ((short*)Cout)[(size_t)rg * N + cg] = f2bf(v);
                } else {
                    if (RESID) v += resid[(size_t)rg * N + cg];
                    ((float*)Cout)[(size_t)rg * N + cg] = v;
                }
            }
        }
}

// ------------------------------------------------- V transpose: qkv bf16 -> Vt[b,h,d,t]
__global__ __launch_bounds__(256) void vt_kernel(const short* __restrict__ qkv,
                                                 short* __restrict__ Vt) {
    int bh = blockIdx.y;
    int b = bh >> 4, hh = bh & 15;
    int t0 = blockIdx.x * 64;
    __shared__ short tile[64 * 72];
    int tc = threadIdx.x & 7, tr = threadIdx.x >> 3;  // tr 0..31
    const short* src = qkv + (size_t)(b * T_SEQ + t0) * (3 * DM) + 2 * DM + hh * DH;
    for (int p = 0; p < 2; ++p) {
        int r = tr + p * 32;
        *(short8*)&tile[r * 72 + tc * 8] = *(const short8*)(src + (size_t)r * (3 * DM) + tc * 8);
    }
    __syncthreads();
    short* dst = Vt + (size_t)bh * DH * T_SEQ + t0;
    for (int p = 0; p < 2; ++p) {
        int d = tr + p * 32;
        short tmp[8];
#pragma unroll
        for (int j = 0; j < 8; ++j) tmp[j] = tile[(tc * 8 + j) * 72 + d];
        *(short8*)(dst + (size_t)d * T_SEQ + tc * 8) =
            short8{tmp[0], tmp[1], tmp[2], tmp[3], tmp[4], tmp[5], tmp[6], tmp[7]};
    }
}

// ------------------------------------------------------- MFMA flash attention (bf16 I/O)
// Block = 64 q-rows of one (b,h); 4 waves x 16 q-rows. BARRIER-FREE: K and V MFMA
// fragments load DIRECTLY from global (per-(b,h) K/V = 256 KB each; T1 swizzle keeps
// the 4 co-resident bh-groups' 2 MB inside the XCD L2; each 8 KB tile's rows are one
// 128B line each -> L1-served for 3 of 4 waves). No LDS staging, no __syncthreads:
// waves progress independently (m169 lesson: staging L2-fit data is pure overhead).
// Pw (P transpose scratch) is wave-local LDS; in-wave DS ordering needs no barrier.
// T1 XCD swizzle: 128 consecutive logical blocks (4 full bh-groups) per XCD L2.
// PV computed as O^T = Vt(A) @ P^T(B). attn f32 stores vectorized from bf16 P tile.
__global__ __launch_bounds__(256) void attn_kernel(const short* __restrict__ qkv,
                                                   const short* __restrict__ Vt,
                                                   float* __restrict__ attn,
                                                   short* __restrict__ ao) {
    // T1 bijective XCD swizzle: nwg=1024 = 8 XCDs x 128
    int blk = (blockIdx.x & 7) * 128 + (blockIdx.x >> 3);
    int qt = (T_SEQ / 64 - 1) - (blk & 31);  // big-q first within bh
    int bh = blk >> 5;
    int b = bh >> 4, hh = bh & 15;
    int q0 = qt * 64;
    int tid = threadIdx.x;
    int wave = tid >> 6, lane = tid & 63;
    int l15 = lane & 15, quad = lane >> 4;

    __shared__ short Ps[4 * 16 * 72];  // per-wave P [q][t], stride 72

    const float scale = 0.125f;
    const short* Qg = qkv + (size_t)(b * T_SEQ + q0) * (3 * DM) + hh * DH;
    const short* Kg = qkv + (size_t)(b * T_SEQ) * (3 * DM) + DM + hh * DH;
    const short* Vg = Vt + (size_t)bh * DH * T_SEQ;

    // Q fragments straight from global (one-time, 2x16B per lane)
    short8 qa[2];
    for (int d0 = 0; d0 < 2; ++d0)
        qa[d0] = *(const short8*)(Qg + (size_t)(wave * 16 + l15) * (3 * DM) + d0 * 32 + quad * 8);

    int ktiles = qt + 1;
    int qrow = q0 + wave * 16 + quad * 4;  // + r

    // ---- pass 1: softmax denominators (K fragments direct from global, no sync)
    float lsum[4] = {0.f, 0.f, 0.f, 0.f};
    for (int kt = 0; kt < ktiles; ++kt) {
        const short* Kt = Kg + (size_t)(kt * 64) * (3 * DM);
        floatx4 sacc[4] = {};
        for (int n0 = 0; n0 < 4; ++n0) {
            const short* kr = Kt + (size_t)(n0 * 16 + l15) * (3 * DM) + quad * 8;
            for (int d0 = 0; d0 < 2; ++d0) {
                short8 kb = *(const short8*)(kr + d0 * 32);
                sacc[n0] = __builtin_amdgcn_mfma_f32_16x16x32_bf16(qa[d0], kb, sacc[n0], 0, 0, 0);
            }
        }
        int kbase = kt * 64 + l15;
        for (int r = 0; r < 4; ++r) {
            float s = 0.f;
            for (int n0 = 0; n0 < 4; ++n0)
                s += (kbase + n0 * 16 <= qrow + r) ? __expf(sacc[n0][r] * scale) : 0.f;
            s += __shfl_xor(s, 1); s += __shfl_xor(s, 2);
            s += __shfl_xor(s, 4); s += __shfl_xor(s, 8);
            lsum[r] += s;
        }
    }
    float invl[4];
    for (int r = 0; r < 4; ++r) invl[r] = 1.0f / lsum[r];

    // ---- pass 2 (K and V fragments direct from global, no sync)
    floatx4 oacc[4] = {};  // O^T tiles: m0 -> d=m0*16+quad*4+r, n -> q=wave*16+l15
    float* abase = attn + (size_t)bh * T_SEQ * T_SEQ;
    short* Pw = &Ps[wave * 1152];
    for (int kt = 0; kt < ktiles; ++kt) {
        const short* Kt = Kg + (size_t)(kt * 64) * (3 * DM);
        floatx4 sacc[4] = {};
        for (int n0 = 0; n0 < 4; ++n0) {
            const short* kr = Kt + (size_t)(n0 * 16 + l15) * (3 * DM) + quad * 8;
            for (int d0 = 0; d0 < 2; ++d0) {
                short8 kb = *(const short8*)(kr + d0 * 32);
                sacc[n0] = __builtin_amdgcn_mfma_f32_16x16x32_bf16(qa[d0], kb, sacc[n0], 0, 0, 0);
            }
        }
        int kbase = kt * 64 + l15;
        for (int n0 = 0; n0 < 4; ++n0)
            for (int r = 0; r < 4; ++r) {
                float p = (kbase + n0 * 16 <= qrow + r)
                              ? __expf(sacc[n0][r] * scale) * invl[r] : 0.f;
                Pw[(quad * 4 + r) * 72 + n0 * 16 + l15] = f2bf(p);
            }
        // O^T += Vt_tile(A) @ P^T(B); V fragment direct from global (L1-served)
        for (int m0 = 0; m0 < 4; ++m0) {
            int d = m0 * 16 + l15;
            const short* vr = Vg + (size_t)d * T_SEQ + kt * 64 + quad * 8;
            for (int k0 = 0; k0 < 2; ++k0) {
                short8 va = *(const short8*)(vr + k0 * 32);
                short8 pb = ld8(&Pw[l15 * 72 + (k0 * 4 + quad) * 8]);
                oacc[m0] = __builtin_amdgcn_mfma_f32_16x16x32_bf16(va, pb, oacc[m0], 0, 0, 0);
            }
        }
        // attn f32 store, vectorized from Pw (each lane: 1 row, 16 cols = 4x float4)
        {
            int ql = lane >> 2, c4 = lane & 3;
            const short* src = &Pw[ql * 72 + c4 * 16];
            float* dst = &abase[(size_t)(q0 + wave * 16 + ql) * T_SEQ + kt * 64 + c4 * 16];
            for (int j = 0; j < 2; ++j) {
                short8 v8 = ld8(src + j * 8);
                float4 f0, f1;
                f0.x = bf2f(v8[0]); f0.y = bf2f(v8[1]); f0.z = bf2f(v8[2]); f0.w = bf2f(v8[3]);
                f1.x = bf2f(v8[4]); f1.y = bf2f(v8[5]); f1.z = bf2f(v8[6]); f1.w = bf2f(v8[7]);
                ((float4*)dst)[j * 2] = f0;
                ((float4*)dst)[j * 2 + 1] = f1;
            }
        }
    }

    // ---- epilogue: transpose O^T -> O rows via Pw (wave-local), store bf16 coalesced
    for (int m0 = 0; m0 < 4; ++m0)
        for (int r = 0; r < 4; ++r)
            Pw[l15 * 72 + m0 * 16 + quad * 4 + r] = f2bf(oacc[m0][r]);
    for (int p = 0; p < 2; ++p) {
        int lq = (lane >> 3) + p * 8;
        int dc = lane & 7;
        short8 o8 = ld8(&Pw[lq * 72 + dc * 8]);
        *(short8*)(ao + (size_t)(b * T_SEQ + q0 + wave * 16 + lq) * DM + hh * DH + dc * 8) = o8;
    }
    // ---- zero-fill causal upper region, float4-vectorized
    {
        int ql = lane >> 2, c4 = lane & 3;
        float4 z = {0.f, 0.f, 0.f, 0.f};
        float* rowp = &abase[(size_t)(q0 + wave * 16 + ql) * T_SEQ];
        for (int col4 = ktiles * 16 + c4; col4 < T_SEQ / 4; col4 += 4)
            ((float4*)rowp)[col4] = z;
    }
}

// ---------------------------------------------------------------- launch
extern "C" void kernel_launch(void* const* d_in, const int* in_sizes, int n_in,
                              void* d_out, int out_size, void* d_ws, size_t ws_size,
                              hipStream_t stream) {
    const float* x     = (const float*)d_in[0];
    const float* ln_g  = (const float*)d_in[1];
    const float* ln_b  = (const float*)d_in[2];
    const float* qkv_w = (const float*)d_in[3];
    const float* qkv_b = (const float*)d_in[4];
    const float* out_w = (const float*)d_in[5];
    const float* out_b = (const float*)d_in[6];

    float* xout = (float*)d_out;
    float* attn = xout + (size_t)ROWS * DM;

    short* h    = (short*)d_ws;                       // [4096,1024] bf16
    short* qkvT = h + (size_t)ROWS * DM;              // [3072,1024] bf16
    short* outT = qkvT + (size_t)(3 * DM) * DM;       // [1024,1024] bf16
    short* qkv  = outT + (size_t)DM * DM;             // [4096,3072] bf16
    short* Vt   = qkv + (size_t)ROWS * 3 * DM;        // [32,64,2048] bf16
    short* ao   = Vt + (size_t)B_SZ * NH * DH * T_SEQ;// [4096,1024] bf16

    ln_kernel<<<ROWS, 256, 0, stream>>>(x, ln_g, ln_b, h);
    wt_kernel<<<dim3(3 * DM / 32, DM / 32), 256, 0, stream>>>(qkv_w, qkvT, DM, 3 * DM);
    wt_kernel<<<dim3(DM / 32, DM / 32), 256, 0, stream>>>(out_w, outT, DM, DM);

    mfma_gemm<false, true><<<dim3(3 * DM / 128, ROWS / 128), 256, 0, stream>>>(
        h, qkvT, qkv_b, nullptr, qkv, ROWS, 3 * DM, DM);

    vt_kernel<<<dim3(T_SEQ / 64, B_SZ * NH), 256, 0, stream>>>(qkv, Vt);

    attn_kernel<<<B_SZ * NH * (T_SEQ / 64), 256, 0, stream>>>(qkv, Vt, attn, ao);

    mfma_gemm<true, false><<<dim3(DM / 128, ROWS / 128), 256, 0, stream>>>(
        ao, outT, out_b, x, xout, ROWS, DM, DM);
}

// Round 5
// 755.410 us; speedup vs baseline: 1.2783x; 1.2783x over previous
//
#include <hip/hip_runtime.h>
#include <math.h>

#define B_SZ 2
#define T_SEQ 2048
#define DM 1024
#define NH 16
#define DH 64
#define ROWS (B_SZ * T_SEQ)  // 4096
#define LN_EPS 1e-5f

typedef __attribute__((ext_vector_type(8))) short short8;
typedef __attribute__((ext_vector_type(4))) float floatx4;

__device__ __forceinline__ short f2bf(float f) {
    union { float f; unsigned u; } v; v.f = f;
    unsigned r = v.u + 0x7fffu + ((v.u >> 16) & 1u);  // RNE
    return (short)(r >> 16);
}
__device__ __forceinline__ float bf2f(short s) {
    union { float f; unsigned u; } v; v.u = ((unsigned)(unsigned short)s) << 16;
    return v.f;
}
__device__ __forceinline__ short8 ld8(const short* p) {  // 8B-aligned pair of b64
    short4 a = *(const short4*)p;
    short4 b = *(const short4*)(p + 4);
    return short8{a.x, a.y, a.z, a.w, b.x, b.y, b.z, b.w};
}
// async 16B global->LDS (lds dest = wave-uniform base + lane*16)
__device__ __forceinline__ void gl2lds16(const void* g, void* l) {
    __builtin_amdgcn_global_load_lds(
        (const __attribute__((address_space(1))) unsigned int*)g,
        (__attribute__((address_space(3))) unsigned int*)l, 16, 0, 0);
}

// ---------------------------------------------------------------- LayerNorm (bf16 out)
__global__ __launch_bounds__(256) void ln_kernel(const float* __restrict__ x,
                                                 const float* __restrict__ g,
                                                 const float* __restrict__ bta,
                                                 short* __restrict__ h) {
    int row = blockIdx.x;
    const float* xr = x + (size_t)row * DM;
    int tid = threadIdx.x;
    float4 v = ((const float4*)xr)[tid];
    float s = v.x + v.y + v.z + v.w;
    float ss = v.x * v.x + v.y * v.y + v.z * v.z + v.w * v.w;
    for (int off = 1; off < 64; off <<= 1) {
        s += __shfl_xor(s, off);
        ss += __shfl_xor(ss, off);
    }
    __shared__ float sbuf[4], ssbuf[4];
    int wave = tid >> 6, lane = tid & 63;
    if (lane == 0) { sbuf[wave] = s; ssbuf[wave] = ss; }
    __syncthreads();
    s = sbuf[0] + sbuf[1] + sbuf[2] + sbuf[3];
    ss = ssbuf[0] + ssbuf[1] + ssbuf[2] + ssbuf[3];
    float mu = s * (1.0f / DM);
    float var = ss * (1.0f / DM) - mu * mu;
    float rs = rsqrtf(var + LN_EPS);
    float4 gg = ((const float4*)g)[tid];
    float4 bb = ((const float4*)bta)[tid];
    short4 o;
    o.x = f2bf((v.x - mu) * rs * gg.x + bb.x);
    o.y = f2bf((v.y - mu) * rs * gg.y + bb.y);
    o.z = f2bf((v.z - mu) * rs * gg.z + bb.z);
    o.w = f2bf((v.w - mu) * rs * gg.w + bb.w);
    *(short4*)&h[(size_t)row * DM + tid * 4] = o;
}

// ------------------------------------------- weight convert+transpose fp32[K,N]->bf16[N,K]
__global__ __launch_bounds__(256) void wt_kernel(const float* __restrict__ W,
                                                 short* __restrict__ Wt, int K, int N) {
    __shared__ float t[32][33];
    int tx = threadIdx.x & 31, ty = threadIdx.x >> 5;  // ty 0..7
    int k0 = blockIdx.y * 32, n0 = blockIdx.x * 32;
    for (int p = 0; p < 4; ++p)
        t[ty + 8 * p][tx] = W[(size_t)(k0 + ty + 8 * p) * N + n0 + tx];
    __syncthreads();
    for (int p = 0; p < 4; ++p)
        Wt[(size_t)(n0 + ty + 8 * p) * K + k0 + tx] = f2bf(t[tx][ty + 8 * p]);
}

// ------------------------------------------------------- bf16 MFMA GEMM (m97 structure)
// C[M,N] = A[M,K]bf16 @ Bt[N,K]bf16^T + bias; 128x128 tile, BK=32, 4 waves x 64x64.
// T1 XCD swizzle on the linearized grid (nwg % 8 == 0 for both call sites).
template <bool RESID, bool BF16_OUT>
__global__ __launch_bounds__(256) void mfma_gemm(const short* __restrict__ A,
                                                 const short* __restrict__ Bt,
                                                 const float* __restrict__ bias,
                                                 const float* __restrict__ resid,
                                                 void* __restrict__ Cout,
                                                 int M, int N, int K) {
    __shared__ short As[128 * 32];
    __shared__ short Bs[128 * 32];
    int tid = threadIdx.x;
    int wave = tid >> 6, lane = tid & 63;
    int l15 = lane & 15, quad = lane >> 4;
    int wm = wave & 1, wn = wave >> 1;
    // T1 bijective XCD swizzle (requires nwg % 8 == 0)
    int nwg = gridDim.x * gridDim.y;
    int bid = blockIdx.y * gridDim.x + blockIdx.x;
    int swz = (bid & 7) * (nwg >> 3) + (bid >> 3);
    int bx = swz % gridDim.x, by = swz / gridDim.x;
    int row0 = by * 128, col0 = bx * 128;

    floatx4 acc[4][4] = {};
    for (int k0 = 0; k0 < K; k0 += 32) {
        __syncthreads();
        for (int i = 0; i < 2; ++i) {
            int c = (wave * 2 + i) * 64 + lane;  // 16B chunk id, 512 per tile
            int row = c >> 2, kc = c & 3;
            gl2lds16(A + (size_t)(row0 + row) * K + k0 + kc * 8, &As[(wave * 2 + i) * 512]);
            gl2lds16(Bt + (size_t)(col0 + row) * K + k0 + kc * 8, &Bs[(wave * 2 + i) * 512]);
        }
        __syncthreads();  // drains vmcnt (global_load_lds) per barrier semantics
        short8 af[4], bfr[4];
        for (int m = 0; m < 4; ++m)
            af[m] = *(const short8*)&As[(wm * 64 + m * 16 + l15) * 32 + quad * 8];
        for (int n = 0; n < 4; ++n)
            bfr[n] = *(const short8*)&Bs[(wn * 64 + n * 16 + l15) * 32 + quad * 8];
        for (int m = 0; m < 4; ++m)
            for (int n = 0; n < 4; ++n)
                acc[m][n] = __builtin_amdgcn_mfma_f32_16x16x32_bf16(af[m], bfr[n], acc[m][n], 0, 0, 0);
    }
    float bias_v[4];
    for (int n = 0; n < 4; ++n) bias_v[n] = bias[col0 + wn * 64 + n * 16 + l15];
    for (int m = 0; m < 4; ++m)
        for (int r = 0; r < 4; ++r) {
            int rg = row0 + wm * 64 + m * 16 + quad * 4 + r;
            for (int n = 0; n < 4; ++n) {
                int cg = col0 + wn * 64 + n * 16 + l15;
                float v = acc[m][n][r] + bias_v[n];
                if (BF16_OUT) {
                    ((short*)Cout)[(size_t)rg * N + cg] = f2bf(v);
                } else {
                    if (RESID) v += resid[(size_t)rg * N + cg];
                    ((float*)Cout)[(size_t)rg * N + cg] = v;
                }
            }
        }
}

// ------------------------------------------------- V transpose: qkv bf16 -> Vt[b,h,d,t]
__global__ __launch_bounds__(256) void vt_kernel(const short* __restrict__ qkv,
                                                 short* __restrict__ Vt) {
    int bh = blockIdx.y;
    int b = bh >> 4, hh = bh & 15;
    int t0 = blockIdx.x * 64;
    __shared__ short tile[64 * 72];
    int tc = threadIdx.x & 7, tr = threadIdx.x >> 3;  // tr 0..31
    const short* src = qkv + (size_t)(b * T_SEQ + t0) * (3 * DM) + 2 * DM + hh * DH;
    for (int p = 0; p < 2; ++p) {
        int r = tr + p * 32;
        *(short8*)&tile[r * 72 + tc * 8] = *(const short8*)(src + (size_t)r * (3 * DM) + tc * 8);
    }
    __syncthreads();
    short* dst = Vt + (size_t)bh * DH * T_SEQ + t0;
    for (int p = 0; p < 2; ++p) {
        int d = tr + p * 32;
        short tmp[8];
#pragma unroll
        for (int j = 0; j < 8; ++j) tmp[j] = tile[(tc * 8 + j) * 72 + d];
        *(short8*)(dst + (size_t)d * T_SEQ + tc * 8) =
            short8{tmp[0], tmp[1], tmp[2], tmp[3], tmp[4], tmp[5], tmp[6], tmp[7]};
    }
}

// ------------------------------------------------------- MFMA flash attention (bf16 I/O)
// Block = 64 q-rows of one (b,h); 4 waves x 16 q-rows. K staged via global_load_lds
// with XOR-swizzled 16B chunks (single-buffered: 25 KB LDS -> 6 blocks/CU; staging IS
// the coalescer — r4's direct-global variant was latency-bound at 430 µs, 2.5% MfmaUtil).
// T1 XCD swizzle: 128 consecutive logical blocks (4 full bh-groups, 2 MB K/V) per XCD L2.
// PV computed as O^T = Vt(A) @ P^T(B). attn f32 stores vectorized from bf16 P tile.
__global__ __launch_bounds__(256) void attn_kernel(const short* __restrict__ qkv,
                                                   const short* __restrict__ Vt,
                                                   float* __restrict__ attn,
                                                   short* __restrict__ ao) {
    // T1 bijective XCD swizzle: nwg=1024 = 8 XCDs x 128
    int blk = (blockIdx.x & 7) * 128 + (blockIdx.x >> 3);
    int qt = (T_SEQ / 64 - 1) - (blk & 31);  // big-q first within bh
    int bh = blk >> 5;
    int b = bh >> 4, hh = bh & 15;
    int q0 = qt * 64;
    int tid = threadIdx.x;
    int wave = tid >> 6, lane = tid & 63;
    int l15 = lane & 15, quad = lane >> 4;

    __shared__ short Ks[64 * 64];      // [t][kchunk^(t&7)] swizzled
    __shared__ short Vs[64 * 64];      // Vt tile [d][tchunk^(d&7)] swizzled
    __shared__ short Ps[4 * 16 * 72];  // per-wave P [q][t], stride 72

    const float scale = 0.125f;
    const short* Qg = qkv + (size_t)(b * T_SEQ + q0) * (3 * DM) + hh * DH;
    const short* Kg = qkv + (size_t)(b * T_SEQ) * (3 * DM) + DM + hh * DH;
    const short* Vg = Vt + (size_t)bh * DH * T_SEQ;

    // Q fragments straight from global (one-time, 2x16B per lane)
    short8 qa[2];
    for (int d0 = 0; d0 < 2; ++d0)
        qa[d0] = *(const short8*)(Qg + (size_t)(wave * 16 + l15) * (3 * DM) + d0 * 32 + quad * 8);

    int ktiles = qt + 1;
    int qrow = q0 + wave * 16 + quad * 4;  // + r

    // ---- pass 1: softmax denominators
    float lsum[4] = {0.f, 0.f, 0.f, 0.f};
    for (int kt = 0; kt < ktiles; ++kt) {
        __syncthreads();
        for (int i = 0; i < 2; ++i) {
            int c = (wave * 2 + i) * 64 + lane;  // 512 chunks: row=c>>3, kc=c&7
            int row = c >> 3, kc = c & 7;
            int kcs = kc ^ (row & 7);
            gl2lds16(Kg + (size_t)(kt * 64 + row) * (3 * DM) + kcs * 8, &Ks[(wave * 2 + i) * 512]);
        }
        __syncthreads();
        floatx4 sacc[4] = {};
        for (int n0 = 0; n0 < 4; ++n0) {
            int row = n0 * 16 + l15;
            for (int d0 = 0; d0 < 2; ++d0) {
                int cc = (d0 * 4 + quad) ^ (row & 7);
                short8 kb = *(const short8*)&Ks[row * 64 + cc * 8];
                sacc[n0] = __builtin_amdgcn_mfma_f32_16x16x32_bf16(qa[d0], kb, sacc[n0], 0, 0, 0);
            }
        }
        int kbase = kt * 64 + l15;
        for (int r = 0; r < 4; ++r) {
            float s = 0.f;
            for (int n0 = 0; n0 < 4; ++n0)
                s += (kbase + n0 * 16 <= qrow + r) ? __expf(sacc[n0][r] * scale) : 0.f;
            s += __shfl_xor(s, 1); s += __shfl_xor(s, 2);
            s += __shfl_xor(s, 4); s += __shfl_xor(s, 8);
            lsum[r] += s;
        }
    }
    float invl[4];
    for (int r = 0; r < 4; ++r) invl[r] = 1.0f / lsum[r];

    // ---- pass 2
    floatx4 oacc[4] = {};  // O^T tiles: m0 -> d=m0*16+quad*4+r, n -> q=wave*16+l15
    float* abase = attn + (size_t)bh * T_SEQ * T_SEQ;
    short* Pw = &Ps[wave * 1152];
    for (int kt = 0; kt < ktiles; ++kt) {
        __syncthreads();
        for (int i = 0; i < 2; ++i) {
            int c = (wave * 2 + i) * 64 + lane;
            int row = c >> 3, kc = c & 7;
            int kcs = kc ^ (row & 7);
            gl2lds16(Kg + (size_t)(kt * 64 + row) * (3 * DM) + kcs * 8, &Ks[(wave * 2 + i) * 512]);
            gl2lds16(Vg + (size_t)row * T_SEQ + kt * 64 + kcs * 8, &Vs[(wave * 2 + i) * 512]);
        }
        __syncthreads();
        floatx4 sacc[4] = {};
        for (int n0 = 0; n0 < 4; ++n0) {
            int row = n0 * 16 + l15;
            for (int d0 = 0; d0 < 2; ++d0) {
                int cc = (d0 * 4 + quad) ^ (row & 7);
                short8 kb = *(const short8*)&Ks[row * 64 + cc * 8];
                sacc[n0] = __builtin_amdgcn_mfma_f32_16x16x32_bf16(qa[d0], kb, sacc[n0], 0, 0, 0);
            }
        }
        int kbase = kt * 64 + l15;
        for (int n0 = 0; n0 < 4; ++n0)
            for (int r = 0; r < 4; ++r) {
                float p = (kbase + n0 * 16 <= qrow + r)
                              ? __expf(sacc[n0][r] * scale) * invl[r] : 0.f;
                Pw[(quad * 4 + r) * 72 + n0 * 16 + l15] = f2bf(p);
            }
        // O^T += Vt_tile(A) @ P^T(B)  (Pw is wave-local: in-wave lgkmcnt orders RAW)
        for (int m0 = 0; m0 < 4; ++m0) {
            int d = m0 * 16 + l15;
            for (int k0 = 0; k0 < 2; ++k0) {
                int cc = (k0 * 4 + quad) ^ (d & 7);
                short8 va = *(const short8*)&Vs[d * 64 + cc * 8];
                short8 pb = ld8(&Pw[l15 * 72 + (k0 * 4 + quad) * 8]);
                oacc[m0] = __builtin_amdgcn_mfma_f32_16x16x32_bf16(va, pb, oacc[m0], 0, 0, 0);
            }
        }
        // attn f32 store, vectorized from Pw (each lane: 1 row, 16 cols = 4x float4)
        {
            int ql = lane >> 2, c4 = lane & 3;
            const short* src = &Pw[ql * 72 + c4 * 16];
            float* dst = &abase[(size_t)(q0 + wave * 16 + ql) * T_SEQ + kt * 64 + c4 * 16];
            for (int j = 0; j < 2; ++j) {
                short8 v8 = ld8(src + j * 8);
                float4 f0, f1;
                f0.x = bf2f(v8[0]); f0.y = bf2f(v8[1]); f0.z = bf2f(v8[2]); f0.w = bf2f(v8[3]);
                f1.x = bf2f(v8[4]); f1.y = bf2f(v8[5]); f1.z = bf2f(v8[6]); f1.w = bf2f(v8[7]);
                ((float4*)dst)[j * 2] = f0;
                ((float4*)dst)[j * 2 + 1] = f1;
            }
        }
    }

    // ---- epilogue: transpose O^T -> O rows via Pw (wave-local), store bf16 coalesced
    for (int m0 = 0; m0 < 4; ++m0)
        for (int r = 0; r < 4; ++r)
            Pw[l15 * 72 + m0 * 16 + quad * 4 + r] = f2bf(oacc[m0][r]);
    for (int p = 0; p < 2; ++p) {
        int lq = (lane >> 3) + p * 8;
        int dc = lane & 7;
        short8 o8 = ld8(&Pw[lq * 72 + dc * 8]);
        *(short8*)(ao + (size_t)(b * T_SEQ + q0 + wave * 16 + lq) * DM + hh * DH + dc * 8) = o8;
    }
    // ---- zero-fill causal upper region, float4-vectorized
    {
        int ql = lane >> 2, c4 = lane & 3;
        float4 z = {0.f, 0.f, 0.f, 0.f};
        float* rowp = &abase[(size_t)(q0 + wave * 16 + ql) * T_SEQ];
        for (int col4 = ktiles * 16 + c4; col4 < T_SEQ / 4; col4 += 4)
            ((float4*)rowp)[col4] = z;
    }
}

// ---------------------------------------------------------------- launch
extern "C" void kernel_launch(void* const* d_in, const int* in_sizes, int n_in,
                              void* d_out, int out_size, void* d_ws, size_t ws_size,
                              hipStream_t stream) {
    const float* x     = (const float*)d_in[0];
    const float* ln_g  = (const float*)d_in[1];
    const float* ln_b  = (const float*)d_in[2];
    const float* qkv_w = (const float*)d_in[3];
    const float* qkv_b = (const float*)d_in[4];
    const float* out_w = (const float*)d_in[5];
    const float* out_b = (const float*)d_in[6];

    float* xout = (float*)d_out;
    float* attn = xout + (size_t)ROWS * DM;

    short* h    = (short*)d_ws;                       // [4096,1024] bf16
    short* qkvT = h + (size_t)ROWS * DM;              // [3072,1024] bf16
    short* outT = qkvT + (size_t)(3 * DM) * DM;       // [1024,1024] bf16
    short* qkv  = outT + (size_t)DM * DM;             // [4096,3072] bf16
    short* Vt   = qkv + (size_t)ROWS * 3 * DM;        // [32,64,2048] bf16
    short* ao   = Vt + (size_t)B_SZ * NH * DH * T_SEQ;// [4096,1024] bf16

    ln_kernel<<<ROWS, 256, 0, stream>>>(x, ln_g, ln_b, h);
    wt_kernel<<<dim3(3 * DM / 32, DM / 32), 256, 0, stream>>>(qkv_w, qkvT, DM, 3 * DM);
    wt_kernel<<<dim3(DM / 32, DM / 32), 256, 0, stream>>>(out_w, outT, DM, DM);

    mfma_gemm<false, true><<<dim3(3 * DM / 128, ROWS / 128), 256, 0, stream>>>(
        h, qkvT, qkv_b, nullptr, qkv, ROWS, 3 * DM, DM);

    vt_kernel<<<dim3(T_SEQ / 64, B_SZ * NH), 256, 0, stream>>>(qkv, Vt);

    attn_kernel<<<B_SZ * NH * (T_SEQ / 64), 256, 0, stream>>>(qkv, Vt, attn, ao);

    mfma_gemm<true, false><<<dim3(DM / 128, ROWS / 128), 256, 0, stream>>>(
        ao, outT, out_b, x, xout, ROWS, DM, DM);
}

// Round 6
// 743.610 us; speedup vs baseline: 1.2986x; 1.0159x over previous
//
#include <hip/hip_runtime.h>
#include <math.h>

#define B_SZ 2
#define T_SEQ 2048
#define DM 1024
#define NH 16
#define DH 64
#define ROWS (B_SZ * T_SEQ)  // 4096
#define LN_EPS 1e-5f

typedef __attribute__((ext_vector_type(8))) short short8;
typedef __attribute__((ext_vector_type(4))) float floatx4;

__device__ __forceinline__ short f2bf(float f) {
    union { float f; unsigned u; } v; v.f = f;
    unsigned r = v.u + 0x7fffu + ((v.u >> 16) & 1u);  // RNE
    return (short)(r >> 16);
}
__device__ __forceinline__ float bf2f(short s) {
    union { float f; unsigned u; } v; v.u = ((unsigned)(unsigned short)s) << 16;
    return v.f;
}
__device__ __forceinline__ short8 ld8(const short* p) {  // 8B-aligned pair of b64
    short4 a = *(const short4*)p;
    short4 b = *(const short4*)(p + 4);
    return short8{a.x, a.y, a.z, a.w, b.x, b.y, b.z, b.w};
}
// async 16B global->LDS (lds dest = wave-uniform base + lane*16)
__device__ __forceinline__ void gl2lds16(const void* g, void* l) {
    __builtin_amdgcn_global_load_lds(
        (const __attribute__((address_space(1))) unsigned int*)g,
        (__attribute__((address_space(3))) unsigned int*)l, 16, 0, 0);
}

// ---------------------------------------------------------------- LayerNorm (bf16 out)
__global__ __launch_bounds__(256) void ln_kernel(const float* __restrict__ x,
                                                 const float* __restrict__ g,
                                                 const float* __restrict__ bta,
                                                 short* __restrict__ h) {
    int row = blockIdx.x;
    const float* xr = x + (size_t)row * DM;
    int tid = threadIdx.x;
    float4 v = ((const float4*)xr)[tid];
    float s = v.x + v.y + v.z + v.w;
    float ss = v.x * v.x + v.y * v.y + v.z * v.z + v.w * v.w;
    for (int off = 1; off < 64; off <<= 1) {
        s += __shfl_xor(s, off);
        ss += __shfl_xor(ss, off);
    }
    __shared__ float sbuf[4], ssbuf[4];
    int wave = tid >> 6, lane = tid & 63;
    if (lane == 0) { sbuf[wave] = s; ssbuf[wave] = ss; }
    __syncthreads();
    s = sbuf[0] + sbuf[1] + sbuf[2] + sbuf[3];
    ss = ssbuf[0] + ssbuf[1] + ssbuf[2] + ssbuf[3];
    float mu = s * (1.0f / DM);
    float var = ss * (1.0f / DM) - mu * mu;
    float rs = rsqrtf(var + LN_EPS);
    float4 gg = ((const float4*)g)[tid];
    float4 bb = ((const float4*)bta)[tid];
    short4 o;
    o.x = f2bf((v.x - mu) * rs * gg.x + bb.x);
    o.y = f2bf((v.y - mu) * rs * gg.y + bb.y);
    o.z = f2bf((v.z - mu) * rs * gg.z + bb.z);
    o.w = f2bf((v.w - mu) * rs * gg.w + bb.w);
    *(short4*)&h[(size_t)row * DM + tid * 4] = o;
}

// ------------------------------------------- weight convert+transpose fp32[K,N]->bf16[N,K]
__global__ __launch_bounds__(256) void wt_kernel(const float* __restrict__ W,
                                                 short* __restrict__ Wt, int K, int N) {
    __shared__ float t[32][33];
    int tx = threadIdx.x & 31, ty = threadIdx.x >> 5;  // ty 0..7
    int k0 = blockIdx.y * 32, n0 = blockIdx.x * 32;
    for (int p = 0; p < 4; ++p)
        t[ty + 8 * p][tx] = W[(size_t)(k0 + ty + 8 * p) * N + n0 + tx];
    __syncthreads();
    for (int p = 0; p < 4; ++p)
        Wt[(size_t)(n0 + ty + 8 * p) * K + k0 + tx] = f2bf(t[tx][ty + 8 * p]);
}

// ------------------------------------------------------- bf16 MFMA GEMM (m97 structure)
// C[M,N] = A[M,K]bf16 @ Bt[N,K]bf16^T + bias; 128x128 tile, BK=32, 4 waves x 64x64.
// T1 XCD swizzle on the linearized grid (nwg % 8 == 0 for both call sites).
template <bool RESID, bool BF16_OUT>
__global__ __launch_bounds__(256) void mfma_gemm(const short* __restrict__ A,
                                                 const short* __restrict__ Bt,
                                                 const float* __restrict__ bias,
                                                 const float* __restrict__ resid,
                                                 void* __restrict__ Cout,
                                                 int M, int N, int K) {
    __shared__ short As[128 * 32];
    __shared__ short Bs[128 * 32];
    int tid = threadIdx.x;
    int wave = tid >> 6, lane = tid & 63;
    int l15 = lane & 15, quad = lane >> 4;
    int wm = wave & 1, wn = wave >> 1;
    // T1 bijective XCD swizzle (requires nwg % 8 == 0)
    int nwg = gridDim.x * gridDim.y;
    int bid = blockIdx.y * gridDim.x + blockIdx.x;
    int swz = (bid & 7) * (nwg >> 3) + (bid >> 3);
    int bx = swz % gridDim.x, by = swz / gridDim.x;
    int row0 = by * 128, col0 = bx * 128;

    floatx4 acc[4][4] = {};
    for (int k0 = 0; k0 < K; k0 += 32) {
        __syncthreads();
        for (int i = 0; i < 2; ++i) {
            int c = (wave * 2 + i) * 64 + lane;  // 16B chunk id, 512 per tile
            int row = c >> 2, kc = c & 3;
            gl2lds16(A + (size_t)(row0 + row) * K + k0 + kc * 8, &As[(wave * 2 + i) * 512]);
            gl2lds16(Bt + (size_t)(col0 + row) * K + k0 + kc * 8, &Bs[(wave * 2 + i) * 512]);
        }
        __syncthreads();  // drains vmcnt (global_load_lds) per barrier semantics
        short8 af[4], bfr[4];
        for (int m = 0; m < 4; ++m)
            af[m] = *(const short8*)&As[(wm * 64 + m * 16 + l15) * 32 + quad * 8];
        for (int n = 0; n < 4; ++n)
            bfr[n] = *(const short8*)&Bs[(wn * 64 + n * 16 + l15) * 32 + quad * 8];
        for (int m = 0; m < 4; ++m)
            for (int n = 0; n < 4; ++n)
                acc[m][n] = __builtin_amdgcn_mfma_f32_16x16x32_bf16(af[m], bfr[n], acc[m][n], 0, 0, 0);
    }
    float bias_v[4];
    for (int n = 0; n < 4; ++n) bias_v[n] = bias[col0 + wn * 64 + n * 16 + l15];
    for (int m = 0; m < 4; ++m)
        for (int r = 0; r < 4; ++r) {
            int rg = row0 + wm * 64 + m * 16 + quad * 4 + r;
            for (int n = 0; n < 4; ++n) {
                int cg = col0 + wn * 64 + n * 16 + l15;
                float v = acc[m][n][r] + bias_v[n];
                if (BF16_OUT) {
                    ((short*)Cout)[(size_t)rg * N + cg] = f2bf(v);
                } else {
                    if (RESID) v += resid[(size_t)rg * N + cg];
                    ((float*)Cout)[(size_t)rg * N + cg] = v;
                }
            }
        }
}

// ------------------------------------------------- V transpose: qkv bf16 -> Vt[b,h,d,t]
__global__ __launch_bounds__(256) void vt_kernel(const short* __restrict__ qkv,
                                                 short* __restrict__ Vt) {
    int bh = blockIdx.y;
    int b = bh >> 4, hh = bh & 15;
    int t0 = blockIdx.x * 64;
    __shared__ short tile[64 * 72];
    int tc = threadIdx.x & 7, tr = threadIdx.x >> 3;  // tr 0..31
    const short* src = qkv + (size_t)(b * T_SEQ + t0) * (3 * DM) + 2 * DM + hh * DH;
    for (int p = 0; p < 2; ++p) {
        int r = tr + p * 32;
        *(short8*)&tile[r * 72 + tc * 8] = *(const short8*)(src + (size_t)r * (3 * DM) + tc * 8);
    }
    __syncthreads();
    short* dst = Vt + (size_t)bh * DH * T_SEQ + t0;
    for (int p = 0; p < 2; ++p) {
        int d = tr + p * 32;
        short tmp[8];
#pragma unroll
        for (int j = 0; j < 8; ++j) tmp[j] = tile[(tc * 8 + j) * 72 + d];
        *(short8*)(dst + (size_t)d * T_SEQ + tc * 8) =
            short8{tmp[0], tmp[1], tmp[2], tmp[3], tmp[4], tmp[5], tmp[6], tmp[7]};
    }
}

// ------------------------------------------------------- MFMA flash attention (bf16 I/O)
// Block = 128 q-rows of one (b,h); 8 waves x 16 q-rows (each wave's code identical to
// the 4-wave version — per-thread VGPR state unchanged). Halves block count ->
// halves K staging instructions and barrier-drain events vs QBLK=64.
// LDS 34 KB -> 4 blocks/CU x 8 waves = 32 waves/CU.
// K staged via global_load_lds with XOR-swizzled 16B chunks (staging IS the coalescer —
// r4's direct-global variant was latency-bound at 430 µs, 2.5% MfmaUtil).
// T1 XCD swizzle: 64 consecutive logical blocks (4 full bh-groups, 2 MB K/V) per XCD L2.
// PV computed as O^T = Vt(A) @ P^T(B). attn f32 stores vectorized from bf16 P tile.
__global__ __launch_bounds__(512) void attn_kernel(const short* __restrict__ qkv,
                                                   const short* __restrict__ Vt,
                                                   float* __restrict__ attn,
                                                   short* __restrict__ ao) {
    // T1 bijective XCD swizzle: nwg=512 = 8 XCDs x 64
    int blk = (blockIdx.x & 7) * 64 + (blockIdx.x >> 3);
    int qt = (T_SEQ / 128 - 1) - (blk & 15);  // big-q first within bh
    int bh = blk >> 4;
    int b = bh >> 4, hh = bh & 15;
    int q0 = qt * 128;
    int tid = threadIdx.x;
    int wave = tid >> 6, lane = tid & 63;  // wave 0..7
    int l15 = lane & 15, quad = lane >> 4;

    __shared__ short Ks[64 * 64];      // [t][kchunk^(t&7)] swizzled
    __shared__ short Vs[64 * 64];      // Vt tile [d][tchunk^(d&7)] swizzled
    __shared__ short Ps[8 * 16 * 72];  // per-wave P [q][t], stride 72 (18 KB)

    const float scale2 = 0.18033688011112042f;  // 0.125 * log2(e)
    const short* Qg = qkv + (size_t)(b * T_SEQ + q0) * (3 * DM) + hh * DH;
    const short* Kg = qkv + (size_t)(b * T_SEQ) * (3 * DM) + DM + hh * DH;
    const short* Vg = Vt + (size_t)bh * DH * T_SEQ;

    // Q fragments straight from global (one-time, 2x16B per lane)
    short8 qa[2];
    for (int d0 = 0; d0 < 2; ++d0)
        qa[d0] = *(const short8*)(Qg + (size_t)(wave * 16 + l15) * (3 * DM) + d0 * 32 + quad * 8);

    int ktiles = 2 * qt + 2;               // block covers q in [q0, q0+128)
    int qrow = q0 + wave * 16 + quad * 4;  // + r

    // staging indices: 512 chunks of 16B per 8KB tile, one chunk per thread
    int srow = tid >> 3, skc = tid & 7;
    int skcs = skc ^ (srow & 7);
    int sdst = (tid >> 6) * 512;  // wave-uniform LDS base (shorts)

    // ---- pass 1: softmax denominators
    float lsum[4] = {0.f, 0.f, 0.f, 0.f};
    for (int kt = 0; kt < ktiles; ++kt) {
        __syncthreads();
        gl2lds16(Kg + (size_t)(kt * 64 + srow) * (3 * DM) + skcs * 8, &Ks[sdst]);
        __syncthreads();
        floatx4 sacc[4] = {};
        for (int n0 = 0; n0 < 4; ++n0) {
            int row = n0 * 16 + l15;
            for (int d0 = 0; d0 < 2; ++d0) {
                int cc = (d0 * 4 + quad) ^ (row & 7);
                short8 kb = *(const short8*)&Ks[row * 64 + cc * 8];
                sacc[n0] = __builtin_amdgcn_mfma_f32_16x16x32_bf16(qa[d0], kb, sacc[n0], 0, 0, 0);
            }
        }
        int kbase = kt * 64 + l15;
        for (int r = 0; r < 4; ++r) {
            float s = 0.f;
            for (int n0 = 0; n0 < 4; ++n0)
                s += (kbase + n0 * 16 <= qrow + r)
                         ? __builtin_amdgcn_exp2f(sacc[n0][r] * scale2) : 0.f;
            s += __shfl_xor(s, 1); s += __shfl_xor(s, 2);
            s += __shfl_xor(s, 4); s += __shfl_xor(s, 8);
            lsum[r] += s;
        }
    }
    float invl[4];
    for (int r = 0; r < 4; ++r) invl[r] = 1.0f / lsum[r];

    // ---- pass 2
    floatx4 oacc[4] = {};  // O^T tiles: m0 -> d=m0*16+quad*4+r, n -> q=wave*16+l15
    float* abase = attn + (size_t)bh * T_SEQ * T_SEQ;
    short* Pw = &Ps[wave * 1152];
    for (int kt = 0; kt < ktiles; ++kt) {
        __syncthreads();
        gl2lds16(Kg + (size_t)(kt * 64 + srow) * (3 * DM) + skcs * 8, &Ks[sdst]);
        gl2lds16(Vg + (size_t)srow * T_SEQ + kt * 64 + skcs * 8, &Vs[sdst]);
        __syncthreads();
        floatx4 sacc[4] = {};
        for (int n0 = 0; n0 < 4; ++n0) {
            int row = n0 * 16 + l15;
            for (int d0 = 0; d0 < 2; ++d0) {
                int cc = (d0 * 4 + quad) ^ (row & 7);
                short8 kb = *(const short8*)&Ks[row * 64 + cc * 8];
                sacc[n0] = __builtin_amdgcn_mfma_f32_16x16x32_bf16(qa[d0], kb, sacc[n0], 0, 0, 0);
            }
        }
        int kbase = kt * 64 + l15;
        for (int n0 = 0; n0 < 4; ++n0)
            for (int r = 0; r < 4; ++r) {
                float p = (kbase + n0 * 16 <= qrow + r)
                              ? __builtin_amdgcn_exp2f(sacc[n0][r] * scale2) * invl[r] : 0.f;
                Pw[(quad * 4 + r) * 72 + n0 * 16 + l15] = f2bf(p);
            }
        // O^T += Vt_tile(A) @ P^T(B)  (Pw is wave-local: in-wave lgkmcnt orders RAW)
        for (int m0 = 0; m0 < 4; ++m0) {
            int d = m0 * 16 + l15;
            for (int k0 = 0; k0 < 2; ++k0) {
                int cc = (k0 * 4 + quad) ^ (d & 7);
                short8 va = *(const short8*)&Vs[d * 64 + cc * 8];
                short8 pb = ld8(&Pw[l15 * 72 + (k0 * 4 + quad) * 8]);
                oacc[m0] = __builtin_amdgcn_mfma_f32_16x16x32_bf16(va, pb, oacc[m0], 0, 0, 0);
            }
        }
        // attn f32 store, vectorized from Pw (each lane: 1 row, 16 cols = 4x float4)
        {
            int ql = lane >> 2, c4 = lane & 3;
            const short* src = &Pw[ql * 72 + c4 * 16];
            float* dst = &abase[(size_t)(q0 + wave * 16 + ql) * T_SEQ + kt * 64 + c4 * 16];
            for (int j = 0; j < 2; ++j) {
                short8 v8 = ld8(src + j * 8);
                float4 f0, f1;
                f0.x = bf2f(v8[0]); f0.y = bf2f(v8[1]); f0.z = bf2f(v8[2]); f0.w = bf2f(v8[3]);
                f1.x = bf2f(v8[4]); f1.y = bf2f(v8[5]); f1.z = bf2f(v8[6]); f1.w = bf2f(v8[7]);
                ((float4*)dst)[j * 2] = f0;
                ((float4*)dst)[j * 2 + 1] = f1;
            }
        }
    }

    // ---- epilogue: transpose O^T -> O rows via Pw (wave-local), store bf16 coalesced
    for (int m0 = 0; m0 < 4; ++m0)
        for (int r = 0; r < 4; ++r)
            Pw[l15 * 72 + m0 * 16 + quad * 4 + r] = f2bf(oacc[m0][r]);
    for (int p = 0; p < 2; ++p) {
        int lq = (lane >> 3) + p * 8;
        int dc = lane & 7;
        short8 o8 = ld8(&Pw[lq * 72 + dc * 8]);
        *(short8*)(ao + (size_t)(b * T_SEQ + q0 + wave * 16 + lq) * DM + hh * DH + dc * 8) = o8;
    }
    // ---- zero-fill causal upper region, float4-vectorized
    {
        int ql = lane >> 2, c4 = lane & 3;
        float4 z = {0.f, 0.f, 0.f, 0.f};
        float* rowp = &abase[(size_t)(q0 + wave * 16 + ql) * T_SEQ];
        for (int col4 = ktiles * 16 + c4; col4 < T_SEQ / 4; col4 += 4)
            ((float4*)rowp)[col4] = z;
    }
}

// ---------------------------------------------------------------- launch
extern "C" void kernel_launch(void* const* d_in, const int* in_sizes, int n_in,
                              void* d_out, int out_size, void* d_ws, size_t ws_size,
                              hipStream_t stream) {
    const float* x     = (const float*)d_in[0];
    const float* ln_g  = (const float*)d_in[1];
    const float* ln_b  = (const float*)d_in[2];
    const float* qkv_w = (const float*)d_in[3];
    const float* qkv_b = (const float*)d_in[4];
    const float* out_w = (const float*)d_in[5];
    const float* out_b = (const float*)d_in[6];

    float* xout = (float*)d_out;
    float* attn = xout + (size_t)ROWS * DM;

    short* h    = (short*)d_ws;                       // [4096,1024] bf16
    short* qkvT = h + (size_t)ROWS * DM;              // [3072,1024] bf16
    short* outT = qkvT + (size_t)(3 * DM) * DM;       // [1024,1024] bf16
    short* qkv  = outT + (size_t)DM * DM;             // [4096,3072] bf16
    short* Vt   = qkv + (size_t)ROWS * 3 * DM;        // [32,64,2048] bf16
    short* ao   = Vt + (size_t)B_SZ * NH * DH * T_SEQ;// [4096,1024] bf16

    ln_kernel<<<ROWS, 256, 0, stream>>>(x, ln_g, ln_b, h);
    wt_kernel<<<dim3(3 * DM / 32, DM / 32), 256, 0, stream>>>(qkv_w, qkvT, DM, 3 * DM);
    wt_kernel<<<dim3(DM / 32, DM / 32), 256, 0, stream>>>(out_w, outT, DM, DM);

    mfma_gemm<false, true><<<dim3(3 * DM / 128, ROWS / 128), 256, 0, stream>>>(
        h, qkvT, qkv_b, nullptr, qkv, ROWS, 3 * DM, DM);

    vt_kernel<<<dim3(T_SEQ / 64, B_SZ * NH), 256, 0, stream>>>(qkv, Vt);

    attn_kernel<<<B_SZ * NH * (T_SEQ / 128), 512, 0, stream>>>(qkv, Vt, attn, ao);

    mfma_gemm<true, false><<<dim3(DM / 128, ROWS / 128), 256, 0, stream>>>(
        ao, outT, out_b, x, xout, ROWS, DM, DM);
}